// Round 1
// baseline (319.008 us; speedup 1.0000x reference)
//
#include <hip/hip_runtime.h>

typedef float f4 __attribute__((ext_vector_type(4)));

#define Wd 1024
#define Hd 1024
#define SH 32            // output rows per block (was 16): halo amp 1.375 -> 1.1875
#define ITER (SH + 6)    // input rows streamed per block (3-row halo each side)

__device__ __forceinline__ f4 load_lum(const float* __restrict__ x0,
                                       const float* __restrict__ x1,
                                       const float* __restrict__ x2, size_t o) {
    f4 a = *(const f4*)(x0 + o);
    f4 g = *(const f4*)(x1 + o);
    f4 c = *(const f4*)(x2 + o);
    return (a + g + c) * (1.f / 3.f);
}

// Barrier-free: horizontal 3-col halo comes from intra-wave shuffles
// (wave = 64 lanes x 4 cols = 256 contiguous columns); lanes 0/63 patch
// the wave-edge halo with a direct (exec-masked) global load. No LDS,
// no __syncthreads -> no vmcnt(0) drain per row; loads pipeline across rows.
__global__ __launch_bounds__(256, 4)
void lvm_stream(const float* __restrict__ x, float* __restrict__ out) {
    const int b    = blockIdx.y;
    const int row0 = blockIdx.x * SH;
    const int tid  = threadIdx.x;
    const int lane = tid & 63;
    const int c0   = tid * 4;

    const float* x0 = x + (size_t)b * 3 * Hd * Wd;
    const float* x1 = x0 + (size_t)Hd * Wd;
    const float* x2 = x1 + (size_t)Hd * Wd;
    float*       ob = out + (size_t)b * Hd * Wd;

    f4 ring1[7], ring2[7];   // per-thread 7-row ring of horizontal sums (static idx only)

#pragma unroll
    for (int i = 0; i < ITER; ++i) {
        const int ri = row0 - 3 + i;          // input (lum) row
        const bool rv = (ri >= 0) && (ri < Hd);   // wave-uniform
        f4 lum = {0.f, 0.f, 0.f, 0.f};
        if (rv) lum = load_lum(x0, x1, x2, (size_t)ri * Wd + c0);

        // neighbor columns via wave shuffles (all 64 lanes active here)
        float v1  = __shfl_up(lum.y, 1);      // col c0-3
        float v2  = __shfl_up(lum.z, 1);      // col c0-2
        float v3  = __shfl_up(lum.w, 1);      // col c0-1
        float v8  = __shfl_down(lum.x, 1);    // col c0+4
        float v9  = __shfl_down(lum.y, 1);    // col c0+5
        float v10 = __shfl_down(lum.z, 1);    // col c0+6

        // wave-edge halo patch (2 lanes/wave, exec-masked; bytes negligible)
        if (lane == 0) {
            v1 = v2 = v3 = 0.f;
            if (rv && c0 >= 4) {
                f4 e = load_lum(x0, x1, x2, (size_t)ri * Wd + (c0 - 4));
                v1 = e.y; v2 = e.z; v3 = e.w;
            }
        }
        if (lane == 63) {
            v8 = v9 = v10 = 0.f;
            if (rv && (c0 + 4) < Wd) {
                f4 e = load_lum(x0, x1, x2, (size_t)ri * Wd + (c0 + 4));
                v8 = e.x; v9 = e.y; v10 = e.z;
            }
        }

        const float v4 = lum.x, v5 = lum.y, v6 = lum.z, v7 = lum.w;

        // horizontal 7-tap sums, sliding window across the 4 output columns
        float s1a = v1 + v2 + v3 + v4 + v5 + v6 + v7;
        float s1b = s1a - v1 + v8;
        float s1c = s1b - v2 + v9;
        float s1d = s1c - v3 + v10;

        float q1 = v1 * v1, q2 = v2 * v2, q3 = v3 * v3, q4 = v4 * v4;
        float q5 = v5 * v5, q6 = v6 * v6, q7 = v7 * v7, q8 = v8 * v8;
        float q9 = v9 * v9, q10 = v10 * v10;
        float s2a = q1 + q2 + q3 + q4 + q5 + q6 + q7;
        float s2b = s2a - q1 + q8;
        float s2c = s2b - q2 + q9;
        float s2d = s2c - q3 + q10;

        ring1[i % 7] = (f4){s1a, s1b, s1c, s1d};   // i is compile-time (full unroll)
        ring2[i % 7] = (f4){s2a, s2b, s2c, s2d};

        if (i >= 6) {                          // ring full -> emit output row
            f4 t1 = ring1[0], t2 = ring2[0];
#pragma unroll
            for (int k = 1; k < 7; ++k) { t1 += ring1[k]; t2 += ring2[k]; }
            const float inv = 1.f / 49.f;
            f4 m = t1 * inv;
            f4 r = t2 * inv - m * m;
            const int ro = row0 + i - 6;
            // output is never re-read: non-temporal store keeps L2/L3 for input halo
            __builtin_nontemporal_store(r, (f4*)(ob + (size_t)ro * Wd + c0));
        }
    }
}

extern "C" void kernel_launch(void* const* d_in, const int* in_sizes, int n_in,
                              void* d_out, int out_size, void* d_ws, size_t ws_size,
                              hipStream_t stream) {
    const float* x = (const float*)d_in[0];
    float* out = (float*)d_out;
    dim3 grid(Hd / SH, 16);   // 32 row-strips x 16 batches = 512 blocks
    lvm_stream<<<grid, dim3(256), 0, stream>>>(x, out);
}

// Round 3
// 299.895 us; speedup vs baseline: 1.0637x; 1.0637x over previous
//
#include <hip/hip_runtime.h>

typedef float f4 __attribute__((ext_vector_type(4)));

#define Wd 1024
#define Hd 1024
#define SH 32            // output rows per block: halo amp 1.1875 (was 1.375 at SH=16)
#define ITER (SH + 6)    // 38 input (lum) rows streamed per block
#define CH 4             // rows staged per barrier (double-buffered: 33 KB LDS)
#define NCH ((ITER + CH - 1) / CH)   // 10 chunks -> 10 barriers (was 22)

// Structure: proven v0 LDS-halo row pipeline, but staged CH rows per
// __syncthreads instead of 1. Each barrier window has 3*CH=12 independent
// float4 loads in flight -> load latency hidden by ILP within the wave
// (fill kernels prove 83% peak HBM at ~10% occupancy, so 2 blocks/CU is ok).
__global__ __launch_bounds__(256, 4)
void lvm_stream(const float* __restrict__ x, float* __restrict__ out) {
    // L[buf][j][i] = lum col (i-4) of chunk-row j; cols -4..1027 zero-padded
    __shared__ __align__(16) float L[2][CH][Wd + 8];

    const int b    = blockIdx.y;
    const int row0 = blockIdx.x * SH;
    const int tid  = threadIdx.x;
    const int c0   = tid * 4;

    const float* x0 = x + (size_t)b * 3 * Hd * Wd;
    const float* x1 = x0 + (size_t)Hd * Wd;
    const float* x2 = x1 + (size_t)Hd * Wd;
    float*       ob = out + (size_t)b * Hd * Wd;

    // zero the horizontal halo columns once (never written again;
    // first chunk's barrier orders these before any read)
    if (tid < 4) {
#pragma unroll
        for (int p = 0; p < 2; ++p)
#pragma unroll
            for (int j = 0; j < CH; ++j) {
                L[p][j][tid] = 0.f;
                L[p][j][Wd + 4 + tid] = 0.f;
            }
    }

    f4 ring1[7], ring2[7];   // per-thread 7-row ring of horizontal sums

#pragma unroll
    for (int c = 0; c < NCH; ++c) {
        const int buf = c & 1;

        // ---- stage CH lum rows: 3*CH independent float4 loads, then LDS writes
        f4 lum[CH];
#pragma unroll
        for (int j = 0; j < CH; ++j) {
            const int i = c * CH + j;             // compile-time after unroll
            if (i < ITER) {
                const int ri = row0 - 3 + i;      // input (lum) row
                lum[j] = (f4){0.f, 0.f, 0.f, 0.f};
                if (ri >= 0 && ri < Hd) {         // wave-uniform
                    const size_t o = (size_t)ri * Wd + c0;
                    f4 a  = *(const f4*)(x0 + o);
                    f4 g  = *(const f4*)(x1 + o);
                    f4 cc = *(const f4*)(x2 + o);
                    lum[j] = (a + g + cc) * (1.f / 3.f);
                }
            }
        }
#pragma unroll
        for (int j = 0; j < CH; ++j) {
            const int i = c * CH + j;
            if (i < ITER) *(f4*)(&L[buf][j][4 + c0]) = lum[j];
        }
        __syncthreads();                          // one barrier per CH rows

        // ---- consume the chunk: horizontal 7-tap sums + vertical ring
#pragma unroll
        for (int j = 0; j < CH; ++j) {
            const int i = c * CH + j;
            if (i < ITER) {
                const float* Lr = &L[buf][j][0];
                // read columns c0-4 .. c0+11 (aligned b128 x3); need c0-3..c0+6
                f4 va = *(const f4*)(Lr + c0);
                f4 vb = *(const f4*)(Lr + c0 + 4);
                f4 vc = *(const f4*)(Lr + c0 + 8);
                float v1 = va.y, v2 = va.z, v3 = va.w;
                float v4 = vb.x, v5 = vb.y, v6 = vb.z, v7 = vb.w;
                float v8 = vc.x, v9 = vc.y, v10 = vc.z;

                float s1a = v1 + v2 + v3 + v4 + v5 + v6 + v7;
                float s1b = s1a - v1 + v8;
                float s1c = s1b - v2 + v9;
                float s1d = s1c - v3 + v10;

                float q1 = v1 * v1, q2 = v2 * v2, q3 = v3 * v3, q4 = v4 * v4;
                float q5 = v5 * v5, q6 = v6 * v6, q7 = v7 * v7, q8 = v8 * v8;
                float q9 = v9 * v9, q10 = v10 * v10;
                float s2a = q1 + q2 + q3 + q4 + q5 + q6 + q7;
                float s2b = s2a - q1 + q8;
                float s2c = s2b - q2 + q9;
                float s2d = s2c - q3 + q10;

                ring1[i % 7] = (f4){s1a, s1b, s1c, s1d};
                ring2[i % 7] = (f4){s2a, s2b, s2c, s2d};

                if (i >= 6) {                     // ring full -> emit output row
                    f4 t1 = ring1[0], t2 = ring2[0];
#pragma unroll
                    for (int k = 1; k < 7; ++k) { t1 += ring1[k]; t2 += ring2[k]; }
                    const float inv = 1.f / 49.f;
                    f4 m = t1 * inv;
                    f4 r = t2 * inv - m * m;
                    const int ro = row0 + i - 6;
                    // output never re-read: keep L2/L3 for input halo
                    __builtin_nontemporal_store(r, (f4*)(ob + (size_t)ro * Wd + c0));
                }
            }
        }
    }
}

extern "C" void kernel_launch(void* const* d_in, const int* in_sizes, int n_in,
                              void* d_out, int out_size, void* d_ws, size_t ws_size,
                              hipStream_t stream) {
    const float* x = (const float*)d_in[0];
    float* out = (float*)d_out;
    dim3 grid(Hd / SH, 16);   // 32 row-strips x 16 batches = 512 blocks
    lvm_stream<<<grid, dim3(256), 0, stream>>>(x, out);
}